// Round 12
// baseline (196.955 us; speedup 1.0000x reference)
//
#include <hip/hip_runtime.h>

// B=16, L=2048, K=24, D=64
typedef _Float16 f16;
typedef _Float16 f16x4 __attribute__((ext_vector_type(4)));
typedef _Float16 f16x8 __attribute__((ext_vector_type(8)));
typedef float f32x4 __attribute__((ext_vector_type(4)));

__device__ __forceinline__ void gl_lds16(const void* g, void* l) {
  __builtin_amdgcn_global_load_lds(
      (__attribute__((address_space(1))) unsigned int*)(g),
      (__attribute__((address_space(3))) unsigned int*)(l), 16, 0, 0);
}

// ---- k_pre0: ALL independent precompute arms in launch #1 (536 blocks).
//   blk 0..255:   uin conversion (pre-swizzled f16 planes for k_w)
//   blk 256..279: phiT[k][e][d] = (f16) m_phi[(k*64+d)*64+e]
//   blk 280..471: Dpre 256-tile Toeplitz tables (8 diag x 24 k), plane 4608:
//                 D'[p][y'] = esm2[510-p-y'], 8 phases x 520 stride.
//   blk 472..535: zero out[]
__global__ __launch_bounds__(256) void k_pre0(const float* __restrict__ in,
                                              const float* __restrict__ m_phi,
                                              const float* __restrict__ ev,
                                              const float* __restrict__ evec,
                                              f16* __restrict__ phiT,
                                              f16* __restrict__ uin,
                                              f16* __restrict__ Dpre,
                                              float* __restrict__ out) {
  __shared__ float esm[512];
  int blk = blockIdx.x;
  int tid = threadIdx.x;
  if (blk < 256) {  // ---- uin conversion (one 128-s x 64-d plane per block)
    int b = blk >> 4, s0 = (blk & 15) * 128;
    f16* up = uin + (size_t)blk * 8192;
#pragma unroll
    for (int v = 0; v < 4; ++v) {
      int flat = v * 256 + tid;
      int row = flat >> 3, cl = flat & 7, cg = cl ^ (row & 7);
      const float* g = in + ((size_t)(b * 2048 + s0 + row)) * 64 + cg * 8;
      float4 u0 = *(const float4*)g;
      float4 u1 = *(const float4*)(g + 4);
      f16x8 h;
      h[0] = (f16)u0.x; h[1] = (f16)u0.y; h[2] = (f16)u0.z; h[3] = (f16)u0.w;
      h[4] = (f16)u1.x; h[5] = (f16)u1.y; h[6] = (f16)u1.z; h[7] = (f16)u1.w;
      *(f16x8*)&up[flat * 8] = h;
    }
    return;
  }
  if (blk < 280) {  // ---- phiT transpose
    int k = blk - 256;
    for (int idx = tid; idx < 4096; idx += 256) {
      int e = idx >> 6, d = idx & 63;
      phiT[k * 4096 + idx] = (f16)m_phi[(k * 64 + d) * 64 + e];
    }
    return;
  }
  if (blk < 472) {  // ---- Dpre blocks (192): 256-tile tables
    int a = blk - 280;
    int diag = a / 24, k = a % 24;
    float s4 = sqrtf(sqrtf(ev[k]));
    int base = diag * 256 - 255;
    {  // load 511 diag values (t = 0..510), zero for v<0
      int v0 = base + tid;
      esm[tid] = (v0 >= 0) ? evec[v0 * 24 + k] * s4 : 0.0f;
      if (tid < 255) {
        int v1 = base + 256 + tid;
        esm[256 + tid] = (v1 >= 0) ? evec[v1 * 24 + k] * s4 : 0.0f;
      }
      if (tid == 255) esm[511] = 0.0f;
    }
    __syncthreads();
    f16* plane = Dpre + (size_t)(diag * 24 + k) * 4608;
    for (int i = tid; i < 4608; i += 256) {
      float val = 0.f;
      if (i < 4160) {
        int p = i / 520, y = i - p * 520;
        int g = 510 - p - y;
        if (g >= 0) val = esm[g];
      }
      plane[i] = (f16)val;
    }
    return;
  }
  // ---- zero-out blocks: 64 blocks x 32768 floats
  float4* o = (float4*)(out + (size_t)(blk - 472) * 32768);
  float4 z4 = {0.f, 0.f, 0.f, 0.f};
#pragma unroll
  for (int i = 0; i < 32; ++i) o[i * 256 + tid] = z4;
}

// ---- k_w: W2T[b][k][e][s] = sum_d in[b][s][d] * m_phi[k*64+d][e]  (f16 out)
// [R15 proven version — unchanged]
__global__ __launch_bounds__(256) void k_w(const f16* __restrict__ uin,
                                           const f16* __restrict__ phiT,
                                           f16* __restrict__ W2T) {
  __shared__ __align__(16) f16 Ubuf[8320];
  __shared__ __align__(16) f16 Psm[64 * 64];
  int wblk = blockIdx.x;
  int s0 = (wblk & 15) * 128;
  int b = (wblk >> 4) & 15;
  int kg = wblk >> 8;  // 0..5
  int tid = threadIdx.x, lane = tid & 63, wv = tid >> 6;
  const f16* up = uin + (size_t)(wblk & 255) * 8192;
  // U stage: contiguous gl_lds (uin pre-swizzled by k_pre0)
#pragma unroll
  for (int v = 0; v < 4; ++v)
    gl_lds16(up + (size_t)(v * 256 + tid) * 8, &Ubuf[(v * 256 + wv * 64) * 8]);
  // P(k0) stage in the same vmcnt group
  {
    int k0 = kg * 4;
#pragma unroll
    for (int v = 0; v < 2; ++v) {
      int flat = v * 256 + tid;
      int row = flat >> 3, cl = flat & 7, cg = cl ^ (row & 7);
      gl_lds16(phiT + (size_t)k0 * 4096 + row * 64 + cg * 8,
               &Psm[(v * 256 + wv * 64) * 8]);
    }
  }
  __syncthreads();  // U + P0 resident
  int wm = wv * 32;
  f16x8 af[2][2];
#pragma unroll
  for (int ks = 0; ks < 2; ++ks)
#pragma unroll
    for (int x = 0; x < 2; ++x) {
      int m = wm + x * 16 + (lane & 15);
      int ch = (ks * 4 + (lane >> 4)) ^ (m & 7);
      af[ks][x] = *(const f16x8*)&Ubuf[m * 64 + ch * 8];
    }
  for (int ki = 0; ki < 4; ++ki) {
    int k = kg * 4 + ki;
    f32x4 zero = {0.f, 0.f, 0.f, 0.f};
    f32x4 acc[2][4];
#pragma unroll
    for (int x = 0; x < 2; ++x)
#pragma unroll
      for (int y = 0; y < 4; ++y) acc[x][y] = zero;
#pragma unroll
    for (int ks = 0; ks < 2; ++ks) {
      f16x8 bf[4];
#pragma unroll
      for (int y = 0; y < 4; ++y) {
        int n = y * 16 + (lane & 15);
        int ch = (ks * 4 + (lane >> 4)) ^ (n & 7);
        bf[y] = *(const f16x8*)&Psm[n * 64 + ch * 8];
      }
#pragma unroll
      for (int x = 0; x < 2; ++x)
#pragma unroll
        for (int y = 0; y < 4; ++y)
          acc[x][y] = __builtin_amdgcn_mfma_f32_16x16x32_f16(af[ks][x], bf[y], acc[x][y], 0, 0, 0);
    }
    __syncthreads();  // Psm reads + (iter0) af Ubuf reads done everywhere
    // transpose C (128 sigma x 64 e) into Ubuf as Csm[e][sigma], stride 130
#pragma unroll
    for (int x = 0; x < 2; ++x)
#pragma unroll
      for (int y = 0; y < 4; ++y) {
        int e = y * 16 + (lane & 15);
        int sg = wm + x * 16 + ((lane >> 4) << 2);
        f16x4 pk;
        pk[0] = (f16)acc[x][y][0]; pk[1] = (f16)acc[x][y][1];
        pk[2] = (f16)acc[x][y][2]; pk[3] = (f16)acc[x][y][3];
        *(f16x4*)&Ubuf[e * 130 + sg] = pk;
      }
    if (ki < 3) {  // prefetch next P (Psm safe to overwrite after sync above)
      int kn = k + 1;
#pragma unroll
      for (int v = 0; v < 2; ++v) {
        int flat = v * 256 + tid;
        int row = flat >> 3, cl = flat & 7, cg = cl ^ (row & 7);
        gl_lds16(phiT + (size_t)kn * 4096 + row * 64 + cg * 8,
                 &Psm[(v * 256 + wv * 64) * 8]);
      }
    }
    __syncthreads();  // Csm visible; P(kn) drained (implicit vmcnt(0))
    // coalesced stores: 1024 chunks of 16B; 16 lanes cover 256B of one e-row
#pragma unroll
    for (int pass = 0; pass < 4; ++pass) {
      int g = pass * 256 + tid;
      int e = g >> 4, ch = g & 15;
      f16x8 val = *(const f16x8*)&Ubuf[e * 130 + ch * 8];
      *(f16x8*)&W2T[((size_t)((b * 24 + k) * 64 + e)) * 2048 + s0 + ch * 8] = val;
    }
  }
}

// ---- k_main: causal block-Toeplitz GEMM, 256-row tiles, e-split x2.
// R27: R26 post-mortem — 97us, MfmaUtil 50.4%, no spill (56 VGPR + 32
// AGPR = 88 unified), prediction matched. Remaining structural overhead:
// launch_bounds(256,4) caps residency at 4 blocks/CU = 1024 slots < 1152
// blocks -> a ~128-block straggler round (~+0.6 T_block of wall).
// Register arithmetic allows FIVE blocks/CU: 88 unified regs <= 512/5 =
// 102 cap; LDS 5 x 25.6 KB = 128 <= 160 KB. (256,5) -> 1280 slots >=
// 1152 -> SINGLE dispatch round, all blocks co-resident, deeper
// inter-block overlap. One-token change from R26.
// Spill gate: VGPR must stay <=~70 / WRITE ~36.9 MB, else the 102-cap
// forced a spill and we revert to (256,4).
__global__ __launch_bounds__(256, 5) void k_main(const f16* __restrict__ Dpre,
                                                 const f16* __restrict__ W2T,
                                                 float* __restrict__ out) {
  __shared__ __align__(16) f16 Bsm[32 * 256];  // 16 KB: 32 e-rows x 256 s
  __shared__ __align__(16) f16 Dsm[4608];      // 9 KB: one diag table
  int b = blockIdx.x;   // 0..15  (FAST dim: pins panel-sharers to one XCD)
  int q = blockIdx.y;   // 0..35
  int eh = blockIdx.z;  // 0..1: e-half
  // decode q -> (st, diag): st has 8-st diags
  int st = 0, off = 0;
  while (off + (8 - st) <= q) { off += 8 - st; ++st; }
  int diag = q - off;
  int mt = st + diag;  // M-tile (256 rows)
  int tid = threadIdx.x, lane = tid & 63, wv = tid >> 6;
  int wm2 = (wv & 1) * 16;       // M phase; m = wm2 + 32x + ..., x in 0..7
  int wn = (wv >> 1) * 16;       // e sub-block within the 32-e half
  int ml = lane & 15, qv = lane >> 4;
  int p520 = (7 - (ml & 7)) * 520;            // phase row in Dsm
  int yb2 = (ml < 8 ? 120 : 112) - wm2;
  int dbase = p520 + yb2 + qv * 8 + 128;      // frag(i=ks-x) at dbase + 32*i

  f32x4 zero = {0.f, 0.f, 0.f, 0.f};
  f32x4 acc[8];
#pragma unroll
  for (int x = 0; x < 8; ++x) acc[x] = zero;

  const f16* dpl = Dpre + (size_t)(diag * 24) * 4608;

#pragma unroll 1
  for (int k = 0; k < 24; ++k) {
    // stage D table: 576 chunks (2x256 all-waves + 64 by wave 0)
    const f16* dk = dpl + (size_t)k * 4608;
    gl_lds16(dk + (size_t)tid * 8, &Dsm[(wv * 64) * 8]);
    gl_lds16(dk + (size_t)(256 + tid) * 8, &Dsm[(256 + wv * 64) * 8]);
    if (wv == 0) gl_lds16(dk + (size_t)(512 + lane) * 8, &Dsm[512 * 8]);
    // stage B tile: 32 e-rows x 256 s (16 KB), XOR-swizzled 16B chunks
    // (32 chunks/row, cg = cl ^ (row & 31))
#pragma unroll
    for (int v = 0; v < 4; ++v) {
      int flat = v * 256 + tid;
      int row = flat >> 5, cl = flat & 31, cg = cl ^ (row & 31);
      gl_lds16(W2T + ((size_t)((b * 24 + k) * 64 + eh * 32 + row)) * 2048 +
                   st * 256 + cg * 8,
               &Bsm[(v * 256 + wv * 64) * 8]);
    }
    __syncthreads();
    // rolling 8-fragment Toeplitz window: w[j] = fragment (ks-7+j);
    // shift by one per ks (SSA-renamed under full unroll), 1 fresh read/ks.
    f16x8 w[8];
#pragma unroll
    for (int j = 0; j < 8; ++j)
      w[j] = *(const f16x8*)&Dsm[dbase + 32 * (j - 7)];
#pragma unroll
    for (int ks = 0; ks < 8; ++ks) {
      if (ks > 0) {
#pragma unroll
        for (int j = 0; j < 7; ++j) w[j] = w[j + 1];
        w[7] = *(const f16x8*)&Dsm[dbase + 32 * ks];
      }
      f16x8 bf;
      {
        int n = wn + ml;  // 0..31 within the staged half
        int cl = (ks * 4 + qv) ^ (n & 31);
        bf = *(const f16x8*)&Bsm[n * 256 + cl * 8];
      }
#pragma unroll
      for (int x = 0; x < 8; ++x)
        acc[x] = __builtin_amdgcn_mfma_f32_16x16x32_f16(
            w[7 - x], bf, acc[x], 0, 0, 0);
    }
    __syncthreads();
  }

  int t0 = mt * 256 + wm2;
  int e = eh * 32 + wn + ml;
#pragma unroll
  for (int x = 0; x < 8; ++x) {
    int rbase = t0 + x * 32 + (qv << 2);
#pragma unroll
    for (int r = 0; r < 4; ++r)
      atomicAdd(&out[((size_t)(b * 2048 + rbase + r)) * 64 + e], acc[x][r]);
  }
}

extern "C" void kernel_launch(void* const* d_in, const int* in_sizes, int n_in,
                              void* d_out, int out_size, void* d_ws, size_t ws_size,
                              hipStream_t stream) {
  const float* inputs = (const float*)d_in[0];  // [16,2048,64]
  const float* m_phi = (const float*)d_in[1];   // [1536,64]
  const float* ev = (const float*)d_in[2];      // [24]
  const float* evec = (const float*)d_in[3];    // [2048,24]
  float* out = (float*)d_out;                   // [16,2048,64] fp32
  char* ws = (char*)d_ws;
  // ws layout: Dpre 1,769,472 (pad to 1,966,080) | phiT | uin | W2T
  f16* Dpre = (f16*)(ws);
  f16* phiT = (f16*)(ws + 1966080);
  f16* uin = (f16*)(ws + 2162688);
  f16* W2T = (f16*)(ws + 6356992);

  hipLaunchKernelGGL(k_pre0, dim3(536), dim3(256), 0, stream,
                     inputs, m_phi, ev, evec, phiT, uin, Dpre, out);
  hipLaunchKernelGGL(k_w, dim3(1536), dim3(256), 0, stream, uin, phiT, W2T);
  hipLaunchKernelGGL(k_main, dim3(16, 36, 2), dim3(256), 0, stream, Dpre, W2T, out);
}

// Round 13
// 173.950 us; speedup vs baseline: 1.1323x; 1.1323x over previous
//
#include <hip/hip_runtime.h>

// B=16, L=2048, K=24, D=64
typedef _Float16 f16;
typedef _Float16 f16x4 __attribute__((ext_vector_type(4)));
typedef _Float16 f16x8 __attribute__((ext_vector_type(8)));
typedef float f32x4 __attribute__((ext_vector_type(4)));

__device__ __forceinline__ void gl_lds16(const void* g, void* l) {
  __builtin_amdgcn_global_load_lds(
      (__attribute__((address_space(1))) unsigned int*)(g),
      (__attribute__((address_space(3))) unsigned int*)(l), 16, 0, 0);
}

// ---- k_pre0: ONLY the arms k_w depends on (280 blocks).
//   blk 0..255:   uin conversion (pre-swizzled f16 planes for k_w)
//   blk 256..279: phiT[k][e][d] = (f16) m_phi[(k*64+d)*64+e]
// (Dpre tables + out-zeroing moved into k_w's launch — they feed only
//  k_main, so they ride k_w's dispatch slack instead of serializing here.)
__global__ __launch_bounds__(256) void k_pre0(const float* __restrict__ in,
                                              const float* __restrict__ m_phi,
                                              f16* __restrict__ phiT,
                                              f16* __restrict__ uin) {
  int blk = blockIdx.x;
  int tid = threadIdx.x;
  if (blk < 256) {  // ---- uin conversion (one 128-s x 64-d plane per block)
    int b = blk >> 4, s0 = (blk & 15) * 128;
    f16* up = uin + (size_t)blk * 8192;
#pragma unroll
    for (int v = 0; v < 4; ++v) {
      int flat = v * 256 + tid;
      int row = flat >> 3, cl = flat & 7, cg = cl ^ (row & 7);
      const float* g = in + ((size_t)(b * 2048 + s0 + row)) * 64 + cg * 8;
      float4 u0 = *(const float4*)g;
      float4 u1 = *(const float4*)(g + 4);
      f16x8 h;
      h[0] = (f16)u0.x; h[1] = (f16)u0.y; h[2] = (f16)u0.z; h[3] = (f16)u0.w;
      h[4] = (f16)u1.x; h[5] = (f16)u1.y; h[6] = (f16)u1.z; h[7] = (f16)u1.w;
      *(f16x8*)&up[flat * 8] = h;
    }
    return;
  }
  // ---- phiT transpose (24 blocks)
  int k = blk - 256;
  for (int idx = tid; idx < 4096; idx += 256) {
    int e = idx >> 6, d = idx & 63;
    phiT[k * 4096 + idx] = (f16)m_phi[(k * 64 + d) * 64 + e];
  }
}

// ---- k_w: W2T[b][k][e][s] = sum_d in[b][s][d] * m_phi[k*64+d][e]  (f16 out)
// [R15 proven core — unchanged]. Grid 1792: blk<1536 = k_w proper;
// blk 1536..1727 = Dpre 256-tile Toeplitz tables (esm aliased onto Ubuf);
// blk 1728..1791 = zero out[]. Arms are k_main-only inputs.
__global__ __launch_bounds__(256) void k_w(const f16* __restrict__ uin,
                                           const f16* __restrict__ phiT,
                                           f16* __restrict__ W2T,
                                           const float* __restrict__ ev,
                                           const float* __restrict__ evec,
                                           f16* __restrict__ Dpre,
                                           float* __restrict__ out) {
  __shared__ __align__(16) f16 Ubuf[8320];
  __shared__ __align__(16) f16 Psm[64 * 64];
  int wblk = blockIdx.x;
  int tid = threadIdx.x;
  if (wblk >= 1728) {  // ---- zero-out arm: 64 blocks x 32768 floats
    float4* o = (float4*)(out + (size_t)(wblk - 1728) * 32768);
    float4 z4 = {0.f, 0.f, 0.f, 0.f};
#pragma unroll
    for (int i = 0; i < 32; ++i) o[i * 256 + tid] = z4;
    return;
  }
  if (wblk >= 1536) {  // ---- Dpre arm (192): 256-tile tables, plane 4608
    float* esm = (float*)Ubuf;  // 512 floats aliased onto Ubuf (2 KB)
    int a = wblk - 1536;
    int diag = a / 24, k = a % 24;
    float s4 = sqrtf(sqrtf(ev[k]));
    int base = diag * 256 - 255;
    {  // load 511 diag values (t = 0..510), zero for v<0
      int v0 = base + tid;
      esm[tid] = (v0 >= 0) ? evec[v0 * 24 + k] * s4 : 0.0f;
      if (tid < 255) {
        int v1 = base + 256 + tid;
        esm[256 + tid] = (v1 >= 0) ? evec[v1 * 24 + k] * s4 : 0.0f;
      }
      if (tid == 255) esm[511] = 0.0f;
    }
    __syncthreads();
    f16* plane = Dpre + (size_t)(diag * 24 + k) * 4608;
    for (int i = tid; i < 4608; i += 256) {
      float val = 0.f;
      if (i < 4160) {
        int p = i / 520, y = i - p * 520;
        int g = 510 - p - y;
        if (g >= 0) val = esm[g];
      }
      plane[i] = (f16)val;
    }
    return;
  }
  // ---- k_w proper (1536 blocks)
  int s0 = (wblk & 15) * 128;
  int b = (wblk >> 4) & 15;
  int kg = wblk >> 8;  // 0..5
  int lane = tid & 63, wv = tid >> 6;
  const f16* up = uin + (size_t)(wblk & 255) * 8192;
  // U stage: contiguous gl_lds (uin pre-swizzled by k_pre0)
#pragma unroll
  for (int v = 0; v < 4; ++v)
    gl_lds16(up + (size_t)(v * 256 + tid) * 8, &Ubuf[(v * 256 + wv * 64) * 8]);
  // P(k0) stage in the same vmcnt group
  {
    int k0 = kg * 4;
#pragma unroll
    for (int v = 0; v < 2; ++v) {
      int flat = v * 256 + tid;
      int row = flat >> 3, cl = flat & 7, cg = cl ^ (row & 7);
      gl_lds16(phiT + (size_t)k0 * 4096 + row * 64 + cg * 8,
               &Psm[(v * 256 + wv * 64) * 8]);
    }
  }
  __syncthreads();  // U + P0 resident
  int wm = wv * 32;
  f16x8 af[2][2];
#pragma unroll
  for (int ks = 0; ks < 2; ++ks)
#pragma unroll
    for (int x = 0; x < 2; ++x) {
      int m = wm + x * 16 + (lane & 15);
      int ch = (ks * 4 + (lane >> 4)) ^ (m & 7);
      af[ks][x] = *(const f16x8*)&Ubuf[m * 64 + ch * 8];
    }
  for (int ki = 0; ki < 4; ++ki) {
    int k = kg * 4 + ki;
    f32x4 zero = {0.f, 0.f, 0.f, 0.f};
    f32x4 acc[2][4];
#pragma unroll
    for (int x = 0; x < 2; ++x)
#pragma unroll
      for (int y = 0; y < 4; ++y) acc[x][y] = zero;
#pragma unroll
    for (int ks = 0; ks < 2; ++ks) {
      f16x8 bf[4];
#pragma unroll
      for (int y = 0; y < 4; ++y) {
        int n = y * 16 + (lane & 15);
        int ch = (ks * 4 + (lane >> 4)) ^ (n & 7);
        bf[y] = *(const f16x8*)&Psm[n * 64 + ch * 8];
      }
#pragma unroll
      for (int x = 0; x < 2; ++x)
#pragma unroll
        for (int y = 0; y < 4; ++y)
          acc[x][y] = __builtin_amdgcn_mfma_f32_16x16x32_f16(af[ks][x], bf[y], acc[x][y], 0, 0, 0);
    }
    __syncthreads();  // Psm reads + (iter0) af Ubuf reads done everywhere
    // transpose C (128 sigma x 64 e) into Ubuf as Csm[e][sigma], stride 130
#pragma unroll
    for (int x = 0; x < 2; ++x)
#pragma unroll
      for (int y = 0; y < 4; ++y) {
        int e = y * 16 + (lane & 15);
        int sg = wm + x * 16 + ((lane >> 4) << 2);
        f16x4 pk;
        pk[0] = (f16)acc[x][y][0]; pk[1] = (f16)acc[x][y][1];
        pk[2] = (f16)acc[x][y][2]; pk[3] = (f16)acc[x][y][3];
        *(f16x4*)&Ubuf[e * 130 + sg] = pk;
      }
    if (ki < 3) {  // prefetch next P (Psm safe to overwrite after sync above)
      int kn = k + 1;
#pragma unroll
      for (int v = 0; v < 2; ++v) {
        int flat = v * 256 + tid;
        int row = flat >> 3, cl = flat & 7, cg = cl ^ (row & 7);
        gl_lds16(phiT + (size_t)kn * 4096 + row * 64 + cg * 8,
                 &Psm[(v * 256 + wv * 64) * 8]);
      }
    }
    __syncthreads();  // Csm visible; P(kn) drained (implicit vmcnt(0))
    // coalesced stores: 1024 chunks of 16B; 16 lanes cover 256B of one e-row
#pragma unroll
    for (int pass = 0; pass < 4; ++pass) {
      int g = pass * 256 + tid;
      int e = g >> 4, ch = g & 15;
      f16x8 val = *(const f16x8*)&Ubuf[e * 130 + ch * 8];
      *(f16x8*)&W2T[((size_t)((b * 24 + k) * 64 + e)) * 2048 + s0 + ch * 8] = val;
    }
  }
}

// ---- k_main: causal block-Toeplitz GEMM, 256-row tiles, e-split x2.
// R28: R27 post-mortem — (256,5)'s 102-reg cap cut arch VGPRs to 48,
// spilling the w[8] window (WRITE 36.9->55.3 MB scratch, 97->119us despite
// single-round 5/CU residency). Register floor of this body is ~88 unified;
// caps below ~120 arch regs spill. REVERTED to the R26-proven (256,4):
// 97us, MfmaUtil 50.4%, no spill. The 1152-vs-1024-slot packing tax
// (~11us) is cheaper than any spill.
__global__ __launch_bounds__(256, 4) void k_main(const f16* __restrict__ Dpre,
                                                 const f16* __restrict__ W2T,
                                                 float* __restrict__ out) {
  __shared__ __align__(16) f16 Bsm[32 * 256];  // 16 KB: 32 e-rows x 256 s
  __shared__ __align__(16) f16 Dsm[4608];      // 9 KB: one diag table
  int b = blockIdx.x;   // 0..15  (FAST dim: pins panel-sharers to one XCD)
  int q = blockIdx.y;   // 0..35
  int eh = blockIdx.z;  // 0..1: e-half
  // decode q -> (st, diag): st has 8-st diags
  int st = 0, off = 0;
  while (off + (8 - st) <= q) { off += 8 - st; ++st; }
  int diag = q - off;
  int mt = st + diag;  // M-tile (256 rows)
  int tid = threadIdx.x, lane = tid & 63, wv = tid >> 6;
  int wm2 = (wv & 1) * 16;       // M phase; m = wm2 + 32x + ..., x in 0..7
  int wn = (wv >> 1) * 16;       // e sub-block within the 32-e half
  int ml = lane & 15, qv = lane >> 4;
  int p520 = (7 - (ml & 7)) * 520;            // phase row in Dsm
  int yb2 = (ml < 8 ? 120 : 112) - wm2;
  int dbase = p520 + yb2 + qv * 8 + 128;      // frag(i=ks-x) at dbase + 32*i

  f32x4 zero = {0.f, 0.f, 0.f, 0.f};
  f32x4 acc[8];
#pragma unroll
  for (int x = 0; x < 8; ++x) acc[x] = zero;

  const f16* dpl = Dpre + (size_t)(diag * 24) * 4608;

#pragma unroll 1
  for (int k = 0; k < 24; ++k) {
    // stage D table: 576 chunks (2x256 all-waves + 64 by wave 0)
    const f16* dk = dpl + (size_t)k * 4608;
    gl_lds16(dk + (size_t)tid * 8, &Dsm[(wv * 64) * 8]);
    gl_lds16(dk + (size_t)(256 + tid) * 8, &Dsm[(256 + wv * 64) * 8]);
    if (wv == 0) gl_lds16(dk + (size_t)(512 + lane) * 8, &Dsm[512 * 8]);
    // stage B tile: 32 e-rows x 256 s (16 KB), XOR-swizzled 16B chunks
    // (32 chunks/row, cg = cl ^ (row & 31))
#pragma unroll
    for (int v = 0; v < 4; ++v) {
      int flat = v * 256 + tid;
      int row = flat >> 5, cl = flat & 31, cg = cl ^ (row & 31);
      gl_lds16(W2T + ((size_t)((b * 24 + k) * 64 + eh * 32 + row)) * 2048 +
                   st * 256 + cg * 8,
               &Bsm[(v * 256 + wv * 64) * 8]);
    }
    __syncthreads();
    // rolling 8-fragment Toeplitz window: w[j] = fragment (ks-7+j);
    // shift by one per ks (SSA-renamed under full unroll), 1 fresh read/ks.
    f16x8 w[8];
#pragma unroll
    for (int j = 0; j < 8; ++j)
      w[j] = *(const f16x8*)&Dsm[dbase + 32 * (j - 7)];
#pragma unroll
    for (int ks = 0; ks < 8; ++ks) {
      if (ks > 0) {
#pragma unroll
        for (int j = 0; j < 7; ++j) w[j] = w[j + 1];
        w[7] = *(const f16x8*)&Dsm[dbase + 32 * ks];
      }
      f16x8 bf;
      {
        int n = wn + ml;  // 0..31 within the staged half
        int cl = (ks * 4 + qv) ^ (n & 31);
        bf = *(const f16x8*)&Bsm[n * 256 + cl * 8];
      }
#pragma unroll
      for (int x = 0; x < 8; ++x)
        acc[x] = __builtin_amdgcn_mfma_f32_16x16x32_f16(
            w[7 - x], bf, acc[x], 0, 0, 0);
    }
    __syncthreads();
  }

  int t0 = mt * 256 + wm2;
  int e = eh * 32 + wn + ml;
#pragma unroll
  for (int x = 0; x < 8; ++x) {
    int rbase = t0 + x * 32 + (qv << 2);
#pragma unroll
    for (int r = 0; r < 4; ++r)
      atomicAdd(&out[((size_t)(b * 2048 + rbase + r)) * 64 + e], acc[x][r]);
  }
}

extern "C" void kernel_launch(void* const* d_in, const int* in_sizes, int n_in,
                              void* d_out, int out_size, void* d_ws, size_t ws_size,
                              hipStream_t stream) {
  const float* inputs = (const float*)d_in[0];  // [16,2048,64]
  const float* m_phi = (const float*)d_in[1];   // [1536,64]
  const float* ev = (const float*)d_in[2];      // [24]
  const float* evec = (const float*)d_in[3];    // [2048,24]
  float* out = (float*)d_out;                   // [16,2048,64] fp32
  char* ws = (char*)d_ws;
  // ws layout: Dpre 1,769,472 (pad to 1,966,080) | phiT | uin | W2T
  f16* Dpre = (f16*)(ws);
  f16* phiT = (f16*)(ws + 1966080);
  f16* uin = (f16*)(ws + 2162688);
  f16* W2T = (f16*)(ws + 6356992);

  hipLaunchKernelGGL(k_pre0, dim3(280), dim3(256), 0, stream,
                     inputs, m_phi, phiT, uin);
  hipLaunchKernelGGL(k_w, dim3(1792), dim3(256), 0, stream,
                     uin, phiT, W2T, ev, evec, Dpre, out);
  hipLaunchKernelGGL(k_main, dim3(16, 36, 2), dim3(256), 0, stream, Dpre, W2T, out);
}